// Round 8
// baseline (57.877 us; speedup 1.0000x reference)
//
#include <hip/hip_runtime.h>
#include <stdint.h>

// Problem constants (fixed by setup_inputs: bs=8, n=4096, c=256, pool=1024)
#define BATCH 8
#define NPTS  4096
#define CH    256
#define QN    1024
#define SUBS  4                  // candidate subsets (waves per query-group)
#define SUBN  (NPTS / SUBS)      // 1024 candidates per wave
#define ITERS (SUBN / 64)        // 16 serial iterations per wave
#define QPW   4                  // queries per wave (amortize candidate loads)

__device__ __forceinline__ float fmul(float a, float b) { return __fmul_rn(a, b); }
__device__ __forceinline__ float fadd(float a, float b) { return __fadd_rn(a, b); }

// reference-exact distance: ((-2*((xx+yy)+zz)) + q_cand) + q_query, no FMA
__device__ __forceinline__ float cdist(const float4 vq, const float4 v) {
  float dot = fadd(fadd(fmul(vq.x, v.x), fmul(vq.y, v.y)), fmul(vq.z, v.z));
  return fadd(fadd(fmul(-2.0f, dot), v.w), vq.w);
}

// order-preserving float->u32 map, idx in low bits -> unique sortable key
__device__ __forceinline__ uint64_t mkkey(float d, uint32_t c) {
  uint32_t bb = __float_as_uint(d);
  bb ^= (uint32_t)((int32_t)bb >> 31) | 0x80000000u;
  return ((uint64_t)bb << 32) | c;
}

__device__ __forceinline__ void cswap(uint64_t& lo, uint64_t& hi) {
  uint64_t mn = hi < lo ? hi : lo;
  uint64_t mx = hi < lo ? lo : hi;
  lo = mn; hi = mx;
}

// wave-min of u64: 4 DPP row_ror steps (VALU pipe) then ^16/^32 via shfl.
__device__ __forceinline__ uint64_t wave_min(uint64_t x) {
#define DPP_MIN_STEP(CTRL)                                                     \
  {                                                                            \
    uint32_t lo = (uint32_t)x, hi = (uint32_t)(x >> 32);                       \
    uint32_t rl = (uint32_t)__builtin_amdgcn_update_dpp((int)lo, (int)lo,      \
                                                        CTRL, 0xF, 0xF, false);\
    uint32_t rh = (uint32_t)__builtin_amdgcn_update_dpp((int)hi, (int)hi,      \
                                                        CTRL, 0xF, 0xF, false);\
    uint64_t o = ((uint64_t)rh << 32) | rl;                                    \
    x = o < x ? o : x;                                                         \
  }
  DPP_MIN_STEP(0x121)  // row_ror:1
  DPP_MIN_STEP(0x122)  // row_ror:2
  DPP_MIN_STEP(0x124)  // row_ror:4
  DPP_MIN_STEP(0x128)  // row_ror:8
#undef DPP_MIN_STEP
  { uint64_t o = (uint64_t)__shfl_xor((long long)x, 16, 64); x = o < x ? o : x; }
  { uint64_t o = (uint64_t)__shfl_xor((long long)x, 32, 64); x = o < x ? o : x; }
  return x;
}

// ---- prep: pack (x,y,z,|v|^2) per point into d_ws (512 KB, L2-resident) ----
__global__ __launch_bounds__(256) void prep_kernel(
    const float* __restrict__ verts,   // [BATCH, NPTS, 3]
    float4*      __restrict__ vc)      // [BATCH*NPTS]
{
  const int p = blockIdx.x * 256 + threadIdx.x;
  const float x = verts[p * 3 + 0];
  const float y = verts[p * 3 + 1];
  const float z = verts[p * 3 + 2];
  const float q = fadd(fadd(fmul(x, x), fmul(y, y)), fmul(z, z));
  vc[p] = make_float4(x, y, z, q);
}

// ---- scan: each wave = 4 queries x 1 candidate subset (1024 cands).
//      One candidate float4 load feeds 4 distance evals. No LDS. ----
#define SBLOCK 256               // 4 waves/block
// wave-jobs = (BATCH*QN/QPW)*SUBS = 8192 -> grid 2048, 8 blocks/CU

__global__ __launch_bounds__(SBLOCK, 8) void knn_scan_kernel(
    const float4* __restrict__ vc,     // [BATCH*NPTS] packed candidates
    const int*    __restrict__ sidx,   // [QN]
    uint64_t*     __restrict__ kbuf,   // [BATCH*QN][SUBS*5] local-top-5 keys
    float*        __restrict__ outV)   // [BATCH, QN, 3]
{
  const int W    = blockIdx.x * (SBLOCK / 64) + (threadIdx.x >> 6);
  const int lane = threadIdx.x & 63;
  const int s    = W & (SUBS - 1);     // subset id 0..3
  const int qg   = W >> 2;             // query group 0..2047 (4 queries each)
  const int batch  = qg >> 8;          // (qg*QPW)/QN
  const int iqbase = (qg << 2) & (QN - 1);
  const float4* vb = vc + (size_t)batch * NPTS;

  float4 vq[QPW];
#pragma unroll
  for (int j = 0; j < QPW; ++j) vq[j] = vb[sidx[iqbase + j]];

  // per-lane top-2 of (d:f32, idx) per query; strict-< == lexicographic (d,idx)
  float    d0[QPW], d1[QPW];
  uint32_t i0[QPW], i1[QPW];
#pragma unroll
  for (int j = 0; j < QPW; ++j) {
    d0[j] = __builtin_inff(); d1[j] = __builtin_inff();
    i0[j] = 0; i1[j] = 0;
  }

#pragma unroll 4
  for (int t = 0; t < ITERS; ++t) {
    const uint32_t c = s * SUBN + t * 64 + lane;
    float4 v = vb[c];                  // 16 B -> 4 query evals
#pragma unroll
    for (int j = 0; j < QPW; ++j) {
      float d = cdist(vq[j], v);
      bool lt = d < d1[j];
      d1[j] = lt ? d : d1[j];
      i1[j] = lt ? c : i1[j];
      bool sw = d1[j] < d0[j];
      float    td = d0[j];  uint32_t ti = i0[j];
      d0[j] = sw ? d1[j] : d0[j];  i0[j] = sw ? i1[j] : i0[j];
      d1[j] = sw ? td    : d1[j];  i1[j] = sw ? ti    : i1[j];
    }
  }

  // per-query local top-5 merge + guard + cheap 16-iter exact fallback
#pragma unroll
  for (int j = 0; j < QPW; ++j) {
    uint64_t k0 = mkkey(d0[j], i0[j]);
    uint64_t k1 = mkkey(d1[j], i1[j]);
    uint64_t prev = 0, l0 = 0, l1 = 0, l2 = 0, l3 = 0, l4 = 0;
#pragma unroll
    for (int r = 0; r < 5; ++r) {
      uint64_t cand = k0 > prev ? k0 : (k1 > prev ? k1 : ~0ull);
      cand = wave_min(cand);
      if (r == 0) l0 = cand;
      if (r == 1) l1 = cand;
      if (r == 2) l2 = cand;
      if (r == 3) l3 = cand;
      if (r == 4) l4 = cand;
      prev = cand;
    }
    // all per-lane drops are > that lane's k1; if every lane's k1 >= local
    // 5th, local top-5 is exact. FP needs >=3 of subset top-5 in one lane
    // (~0.24%); fallback is only 16 iterations -> no heavy tail.
    if (__any(k1 < l4)) {
      uint64_t b0 = ~0ull, b1 = ~0ull, b2 = ~0ull, b3 = ~0ull, b4 = ~0ull;
      for (int t = 0; t < ITERS; ++t) {
        const uint32_t c = s * SUBN + t * 64 + lane;
        uint64_t key = mkkey(cdist(vq[j], vb[c]), c);
        b4 = key < b4 ? key : b4;
        cswap(b3, b4); cswap(b2, b3); cswap(b1, b2); cswap(b0, b1);
      }
      prev = 0;
#pragma unroll
      for (int r = 0; r < 5; ++r) {
        uint64_t cand = b0 > prev ? b0
                      : b1 > prev ? b1
                      : b2 > prev ? b2
                      : b3 > prev ? b3
                      : b4 > prev ? b4 : ~0ull;
        cand = wave_min(cand);
        if (r == 0) l0 = cand;
        if (r == 1) l1 = cand;
        if (r == 2) l2 = cand;
        if (r == 3) l3 = cand;
        if (r == 4) l4 = cand;
        prev = cand;
      }
    }
    if (lane == 0) {
      uint64_t* kq = kbuf + ((size_t)(batch * QN + iqbase + j)) * (SUBS * 5) + s * 5;
      kq[0] = l0; kq[1] = l1; kq[2] = l2; kq[3] = l3; kq[4] = l4;
    }
  }

  if (s == 0 && lane < 3) {
#pragma unroll
    for (int j = 0; j < QPW; ++j) {
      float val = lane == 0 ? vq[j].x : (lane == 1 ? vq[j].y : vq[j].z);
      outV[((size_t)batch * QN + iqbase + j) * 3 + lane] = val;
    }
  }
}

// ---- gather: merge the 20 subset keys (lanes 0..19), then feature burst ----
// rank-0 of the merged list is the reference's dropped column (its global
// minimum, ties by index) -- exactly [:, :, 1:] semantics.
#define GBLOCK 256
#define GQPB   (GBLOCK / 64)   // 4 queries per block

__global__ __launch_bounds__(GBLOCK) void knn_gather_kernel(
    const float*    __restrict__ feat,  // [BATCH, NPTS, CH]
    const uint64_t* __restrict__ kbuf,  // [BATCH*QN][SUBS*5]
    float*          __restrict__ outF)  // [BATCH, QN, CH]
{
  const int gq   = blockIdx.x * GQPB + (threadIdx.x >> 6);  // 0..8191
  const int lane = threadIdx.x & 63;

  uint64_t key = lane < SUBS * 5 ? kbuf[(size_t)gq * (SUBS * 5) + lane] : ~0ull;
  uint64_t prev = 0, nb1 = 0, nb2 = 0, nb3 = 0, nb4 = 0;
#pragma unroll
  for (int r = 0; r < 5; ++r) {
    uint64_t cand = key > prev ? key : ~0ull;
    cand = wave_min(cand);
    if (r == 1) nb1 = cand;   // r==0 dropped (reference [:, :, 1:])
    if (r == 2) nb2 = cand;
    if (r == 3) nb3 = cand;
    if (r == 4) nb4 = cand;
    prev = cand;
  }

  const int batch = gq >> 10;          // QN = 1024
  const float* fb = feat + (size_t)batch * NPTS * CH;
  const int col = lane * 4;            // 64 lanes * 4 = 256 channels

  float4 f1 = *(const float4*)(fb + (size_t)(uint32_t)nb1 * CH + col);
  float4 f2 = *(const float4*)(fb + (size_t)(uint32_t)nb2 * CH + col);
  float4 f3 = *(const float4*)(fb + (size_t)(uint32_t)nb3 * CH + col);
  float4 f4 = *(const float4*)(fb + (size_t)(uint32_t)nb4 * CH + col);
  float4 r;
  r.x = fmaxf(fmaxf(f1.x, f2.x), fmaxf(f3.x, f4.x));
  r.y = fmaxf(fmaxf(f1.y, f2.y), fmaxf(f3.y, f4.y));
  r.z = fmaxf(fmaxf(f1.z, f2.z), fmaxf(f3.z, f4.z));
  r.w = fmaxf(fmaxf(f1.w, f2.w), fmaxf(f3.w, f4.w));
  *(float4*)(outF + (size_t)gq * CH + col) = r;
}

extern "C" void kernel_launch(void* const* d_in, const int* in_sizes, int n_in,
                              void* d_out, int out_size, void* d_ws, size_t ws_size,
                              hipStream_t stream) {
  const float* verts = (const float*)d_in[0];
  const float* feat  = (const float*)d_in[1];
  const int*   sidx  = (const int*)d_in[2];
  float* outV = (float*)d_out;                          // [BATCH, QN, 3]
  float* outF = (float*)d_out + (size_t)BATCH * QN * 3; // [BATCH, QN, CH]

  float4*   vc   = (float4*)d_ws;                       // 512 KB
  uint64_t* kbuf = (uint64_t*)((char*)d_ws + (size_t)BATCH * NPTS * sizeof(float4));
                                                        // 8192*20*8B = 1.31 MB

  prep_kernel<<<dim3(BATCH * NPTS / 256), dim3(256), 0, stream>>>(verts, vc);
  knn_scan_kernel<<<dim3((BATCH * QN / QPW) * SUBS / (SBLOCK / 64)),
                    dim3(SBLOCK), 0, stream>>>(vc, sidx, kbuf, outV);
  knn_gather_kernel<<<dim3(BATCH * QN / GQPB), dim3(GBLOCK), 0, stream>>>(
      feat, kbuf, outF);
}

// Round 9
// 55.864 us; speedup vs baseline: 1.0360x; 1.0360x over previous
//
#include <hip/hip_runtime.h>
#include <stdint.h>

// Problem constants (fixed by setup_inputs: bs=8, n=4096, c=256, pool=1024)
#define BATCH 8
#define NPTS  4096
#define CH    256
#define QN    1024
#define QPW   2                  // queries per wave
#define SUBS  2                  // candidate subsets per query
#define SUBN  (NPTS / SUBS)      // 2048 candidates per wave
#define ITERS (SUBN / 64)        // 32 serial iterations per wave
#define KSLOT 3                  // keys kept per lane per query

__device__ __forceinline__ float fmul(float a, float b) { return __fmul_rn(a, b); }
__device__ __forceinline__ float fadd(float a, float b) { return __fadd_rn(a, b); }

// reference-exact distance: ((-2*((xx+yy)+zz)) + q_cand) + q_query, no FMA
__device__ __forceinline__ float cdist(const float4 vq, const float4 v) {
  float dot = fadd(fadd(fmul(vq.x, v.x), fmul(vq.y, v.y)), fmul(vq.z, v.z));
  return fadd(fadd(fmul(-2.0f, dot), v.w), vq.w);
}

// order-preserving float->u32 map, idx in low bits -> unique sortable key
__device__ __forceinline__ uint64_t mkkey(float d, uint32_t c) {
  uint32_t bb = __float_as_uint(d);
  bb ^= (uint32_t)((int32_t)bb >> 31) | 0x80000000u;
  return ((uint64_t)bb << 32) | c;
}

__device__ __forceinline__ void cswap(uint64_t& lo, uint64_t& hi) {
  uint64_t mn = hi < lo ? hi : lo;
  uint64_t mx = hi < lo ? lo : hi;
  lo = mn; hi = mx;
}

// wave-min of u64: 4 DPP row_ror steps (VALU pipe) then ^16/^32 via shfl.
__device__ __forceinline__ uint64_t wave_min(uint64_t x) {
#define DPP_MIN_STEP(CTRL)                                                     \
  {                                                                            \
    uint32_t lo = (uint32_t)x, hi = (uint32_t)(x >> 32);                       \
    uint32_t rl = (uint32_t)__builtin_amdgcn_update_dpp((int)lo, (int)lo,      \
                                                        CTRL, 0xF, 0xF, false);\
    uint32_t rh = (uint32_t)__builtin_amdgcn_update_dpp((int)hi, (int)hi,      \
                                                        CTRL, 0xF, 0xF, false);\
    uint64_t o = ((uint64_t)rh << 32) | rl;                                    \
    x = o < x ? o : x;                                                         \
  }
  DPP_MIN_STEP(0x121)  // row_ror:1
  DPP_MIN_STEP(0x122)  // row_ror:2
  DPP_MIN_STEP(0x124)  // row_ror:4
  DPP_MIN_STEP(0x128)  // row_ror:8
#undef DPP_MIN_STEP
  { uint64_t o = (uint64_t)__shfl_xor((long long)x, 16, 64); x = o < x ? o : x; }
  { uint64_t o = (uint64_t)__shfl_xor((long long)x, 32, 64); x = o < x ? o : x; }
  return x;
}

// ---- prep: pack (x,y,z,|v|^2) per point into d_ws (512 KB, L2-resident) ----
__global__ __launch_bounds__(256) void prep_kernel(
    const float* __restrict__ verts,   // [BATCH, NPTS, 3]
    float4*      __restrict__ vc)      // [BATCH*NPTS]
{
  const int p = blockIdx.x * 256 + threadIdx.x;
  const float x = verts[p * 3 + 0];
  const float y = verts[p * 3 + 1];
  const float z = verts[p * 3 + 2];
  const float q = fadd(fadd(fmul(x, x), fmul(y, y)), fmul(z, z));
  vc[p] = make_float4(x, y, z, q);
}

// ---- scan: PURE streaming. Wave = 2 queries x 2048-candidate subset.
//      Per-lane top-3 (f32,idx) per query; dump keys; NO cross-lane ops. ----
#define SBLOCK 256               // 4 waves/block
// wave-jobs = (BATCH*QN/QPW)*SUBS = 8192 -> grid 2048, 8 blocks/CU

__global__ __launch_bounds__(SBLOCK, 8) void knn_scan_kernel(
    const float4* __restrict__ vc,     // [BATCH*NPTS] packed candidates
    const int*    __restrict__ sidx,   // [QN]
    uint64_t*     __restrict__ kbuf,   // [8192][SUBS][KSLOT][64] keys
    float*        __restrict__ outV)   // [BATCH, QN, 3]
{
  const int W    = blockIdx.x * (SBLOCK / 64) + (threadIdx.x >> 6);
  const int lane = threadIdx.x & 63;
  const int s    = W & (SUBS - 1);     // subset id
  const int qg   = W >> 1;             // query group 0..4095 (2 queries each)
  const int batch  = qg >> 9;          // (qg*QPW)/QN
  const int iqbase = (qg << 1) & (QN - 1);
  const float4* vb = vc + (size_t)batch * NPTS;

  float4 vq[QPW];
#pragma unroll
  for (int j = 0; j < QPW; ++j) vq[j] = vb[sidx[iqbase + j]];

  // per-lane top-3 of (d:f32, idx); strict-< insert == lexicographic (d,idx)
  float    d0[QPW], d1[QPW], d2[QPW];
  uint32_t i0[QPW], i1[QPW], i2[QPW];
#pragma unroll
  for (int j = 0; j < QPW; ++j) {
    d0[j] = __builtin_inff(); d1[j] = __builtin_inff(); d2[j] = __builtin_inff();
    i0[j] = 0; i1[j] = 0; i2[j] = 0;
  }

#pragma unroll 8
  for (int t = 0; t < ITERS; ++t) {
    const uint32_t c = s * SUBN + t * 64 + lane;
    float4 v = vb[c];                  // coalesced 16 B, L2-hot
#pragma unroll
    for (int j = 0; j < QPW; ++j) {
      float d = cdist(vq[j], v);
      bool lt = d < d2[j];
      d2[j] = lt ? d : d2[j];
      i2[j] = lt ? c : i2[j];
      bool s1 = d2[j] < d1[j];
      { float td = d1[j]; uint32_t ti = i1[j];
        d1[j] = s1 ? d2[j] : d1[j];  i1[j] = s1 ? i2[j] : i1[j];
        d2[j] = s1 ? td    : d2[j];  i2[j] = s1 ? ti    : i2[j]; }
      bool s0 = d1[j] < d0[j];
      { float td = d0[j]; uint32_t ti = i0[j];
        d0[j] = s0 ? d1[j] : d0[j];  i0[j] = s0 ? i1[j] : i0[j];
        d1[j] = s0 ? td    : d1[j];  i1[j] = s0 ? ti    : i1[j]; }
    }
  }

  // dump 3 keys per query (coalesced u64 stores); no merge, no guard here
#pragma unroll
  for (int j = 0; j < QPW; ++j) {
    const size_t q = (size_t)batch * QN + iqbase + j;
    uint64_t* kq = kbuf + ((q * SUBS + s) * KSLOT) * 64 + lane;
    kq[0 * 64] = mkkey(d0[j], i0[j]);
    kq[1 * 64] = mkkey(d1[j], i1[j]);
    kq[2 * 64] = mkkey(d2[j], i2[j]);
  }

  if (s == 0 && lane < 3) {
#pragma unroll
    for (int j = 0; j < QPW; ++j) {
      float val = lane == 0 ? vq[j].x : (lane == 1 ? vq[j].y : vq[j].z);
      outV[((size_t)batch * QN + iqbase + j) * 3 + lane] = val;
    }
  }
}

// ---- gather: merge 384 keys/query, guard, rare exact rescan, feature burst --
#define GBLOCK 256
#define GQPB   (GBLOCK / 64)   // 4 queries per block

__global__ __launch_bounds__(GBLOCK) void knn_gather_kernel(
    const float*    __restrict__ feat,  // [BATCH, NPTS, CH]
    const uint64_t* __restrict__ kbuf,  // [8192][SUBS][KSLOT][64]
    const float4*   __restrict__ vc,    // [BATCH*NPTS]
    const int*      __restrict__ sidx,  // [QN]
    float*          __restrict__ outF)  // [BATCH, QN, CH]
{
  const int gq   = blockIdx.x * GQPB + (threadIdx.x >> 6);  // 0..8191
  const int lane = threadIdx.x & 63;

  // load this lane's 6 keys (2 subsets x 3 slots), all coalesced
  uint64_t k[SUBS * KSLOT];
#pragma unroll
  for (int s = 0; s < SUBS; ++s)
#pragma unroll
    for (int t = 0; t < KSLOT; ++t)
      k[s * KSLOT + t] = kbuf[(((size_t)gq * SUBS + s) * KSLOT + t) * 64 + lane];

  // top-5 of the 384 keys: 5 rounds of "min key strictly greater than prev"
  uint64_t prev = 0, nb1 = 0, nb2 = 0, nb3 = 0, nb4 = 0;
#pragma unroll
  for (int r = 0; r < 5; ++r) {
    uint64_t cand = ~0ull;
#pragma unroll
    for (int t = 0; t < SUBS * KSLOT; ++t)
      cand = (k[t] > prev && k[t] < cand) ? k[t] : cand;
    cand = wave_min(cand);
    if (r == 1) nb1 = cand;   // r==0 is the reference's dropped column
    if (r == 2) nb2 = cand;
    if (r == 3) nb3 = cand;
    if (r == 4) nb4 = cand;
    prev = cand;
  }

  const int batch = gq >> 10;          // QN = 1024
  // guard: per-lane per-subset slot-2 key is a lower bound on all drops;
  // if any such bound < merged 5th, fall back to a full exact rescan.
  bool risk = (k[0 * KSLOT + 2] < nb4) || (k[1 * KSLOT + 2] < nb4);
  if (__any(risk)) {
    const float4* vb = vc + (size_t)batch * NPTS;
    const float4 vq = vb[sidx[gq & (QN - 1)]];
    uint64_t b0 = ~0ull, b1 = ~0ull, b2 = ~0ull, b3 = ~0ull, b4 = ~0ull;
    for (int t = 0; t < NPTS / 64; ++t) {
      const uint32_t c = t * 64 + lane;
      uint64_t key = mkkey(cdist(vq, vb[c]), c);
      b4 = key < b4 ? key : b4;
      cswap(b3, b4); cswap(b2, b3); cswap(b1, b2); cswap(b0, b1);
    }
    prev = 0;
#pragma unroll
    for (int r = 0; r < 5; ++r) {
      uint64_t cand = b0 > prev ? b0
                    : b1 > prev ? b1
                    : b2 > prev ? b2
                    : b3 > prev ? b3
                    : b4 > prev ? b4 : ~0ull;
      cand = wave_min(cand);
      if (r == 1) nb1 = cand;
      if (r == 2) nb2 = cand;
      if (r == 3) nb3 = cand;
      if (r == 4) nb4 = cand;
      prev = cand;
    }
  }

  const float* fb = feat + (size_t)batch * NPTS * CH;
  const int col = lane * 4;            // 64 lanes * 4 = 256 channels

  float4 f1 = *(const float4*)(fb + (size_t)(uint32_t)nb1 * CH + col);
  float4 f2 = *(const float4*)(fb + (size_t)(uint32_t)nb2 * CH + col);
  float4 f3 = *(const float4*)(fb + (size_t)(uint32_t)nb3 * CH + col);
  float4 f4 = *(const float4*)(fb + (size_t)(uint32_t)nb4 * CH + col);
  float4 r;
  r.x = fmaxf(fmaxf(f1.x, f2.x), fmaxf(f3.x, f4.x));
  r.y = fmaxf(fmaxf(f1.y, f2.y), fmaxf(f3.y, f4.y));
  r.z = fmaxf(fmaxf(f1.z, f2.z), fmaxf(f3.z, f4.z));
  r.w = fmaxf(fmaxf(f1.w, f2.w), fmaxf(f3.w, f4.w));
  *(float4*)(outF + (size_t)gq * CH + col) = r;
}

extern "C" void kernel_launch(void* const* d_in, const int* in_sizes, int n_in,
                              void* d_out, int out_size, void* d_ws, size_t ws_size,
                              hipStream_t stream) {
  const float* verts = (const float*)d_in[0];
  const float* feat  = (const float*)d_in[1];
  const int*   sidx  = (const int*)d_in[2];
  float* outV = (float*)d_out;                          // [BATCH, QN, 3]
  float* outF = (float*)d_out + (size_t)BATCH * QN * 3; // [BATCH, QN, CH]

  float4*   vc   = (float4*)d_ws;                       // 512 KB
  uint64_t* kbuf = (uint64_t*)((char*)d_ws + (size_t)BATCH * NPTS * sizeof(float4));
                                  // 8192 * 2 * 3 * 64 * 8 B = 25.2 MB

  prep_kernel<<<dim3(BATCH * NPTS / 256), dim3(256), 0, stream>>>(verts, vc);
  knn_scan_kernel<<<dim3((BATCH * QN / QPW) * SUBS / (SBLOCK / 64)),
                    dim3(SBLOCK), 0, stream>>>(vc, sidx, kbuf, outV);
  knn_gather_kernel<<<dim3(BATCH * QN / GQPB), dim3(GBLOCK), 0, stream>>>(
      feat, kbuf, vc, sidx, outF);
}